// Round 3
// baseline (64798.798 us; speedup 1.0000x reference)
//
#include <hip/hip_runtime.h>
#include <math.h>

#define NROWS 4096
#define DZ    128
#define DH    512
#define VOC   64
#define DE    128
#define MAXLEN 128
#define PAD_T 0
#define SOS_T 1
#define EOS_T 2

// ---------------- transpose: in [R][C] -> out [C][R] ----------------
__global__ void transpose_k(const float* __restrict__ in, float* __restrict__ out,
                            int R, int C) {
  __shared__ float tile[32][33];
  int cb = blockIdx.x * 32, rb = blockIdx.y * 32;
  int tx = threadIdx.x, ty = threadIdx.y;  // blockDim (32,8)
  #pragma unroll
  for (int i = ty; i < 32; i += 8)
    tile[i][tx] = in[(size_t)(rb + i) * C + (cb + tx)];
  __syncthreads();
  #pragma unroll
  for (int i = ty; i < 32; i += 8)
    out[(size_t)(cb + i) * R + (rb + tx)] = tile[tx][i];
}

// ---------------- repack h2v: in [Rn][K] -> P[((k>>2)*Rn + r)*4 + (k&3)] -----
__global__ void repack_k(const float* __restrict__ in, float* __restrict__ out,
                         int Rn, int K) {
  int k = blockIdx.y * 128 + threadIdx.x;
  int r = blockIdx.x;
  out[((size_t)(k >> 2) * Rn + r) * 4 + (k & 3)] = in[(size_t)r * K + k];
}

// ---------------- repack weights: W [3*DH][K] -> W2 [DH/8][K][3][8] ----------
// W2[((jt*K + k)*3 + g)*8 + jj] = W[(g*DH + jt*8 + jj)*K + k]
__global__ void repack_w(const float* __restrict__ in, float* __restrict__ out,
                         int K) {
  size_t i = (size_t)blockIdx.x * 256 + threadIdx.x;  // total 64*K*24
  int jj = (int)(i & 7);
  int g  = (int)((i >> 3) % 3);
  size_t rest = i / 24;
  int k  = (int)(rest % K);
  int jt = (int)(rest / K);
  out[i] = in[(size_t)(g * DH + jt * 8 + jj) * K + k];
}

// ---------------- G0[v][jj] = sum_k emb[v][k] * WiT0[k][jj] + bi[jj] ---------
__global__ __launch_bounds__(256) void build_g0(
    const float* __restrict__ emb, const float* __restrict__ WiT0,
    const float* __restrict__ bi, float* __restrict__ G0) {
  int jj = blockIdx.y * 256 + threadIdx.x;   // grid.y = 3*DH/256
  int v = blockIdx.x;                        // grid.x = VOC
  float acc = bi[jj];
  const float* e = emb + (size_t)v * DE;     // wave-uniform -> s_load
  #pragma unroll 4
  for (int k = 0; k < DE; ++k)
    acc = fmaf(e[k], WiT0[(size_t)k * (3 * DH) + jj], acc);
  G0[(size_t)v * (3 * DH) + jj] = acc;
}

// ---------------- init: h0 = Z @ z2h_w^T + b; packed state init --------------
// state layout P4: element (k,r) at [((k>>2)*NROWS + r)*4 + (k&3)]
__global__ __launch_bounds__(256) void init_kernel(
    const float* __restrict__ Z, const float* __restrict__ z2hT,
    const float* __restrict__ z2h_b,
    float* __restrict__ h1, float* __restrict__ h2, float* __restrict__ h3,
    int* __restrict__ tok, int* __restrict__ eos, int* __restrict__ outi) {
  int lane = threadIdx.x & 63;
  int wave = __builtin_amdgcn_readfirstlane((int)(threadIdx.x >> 6));
  int r = blockIdx.x * 4 + wave;          // grid.x = NROWS/4
  int j = blockIdx.y * 64 + lane;         // grid.y = DH/64
  float acc = z2h_b[j];
  const float* zr = Z + (size_t)r * DZ;   // wave-uniform -> s_load
  #pragma unroll 4
  for (int k = 0; k < DZ; ++k)
    acc = fmaf(zr[k], z2hT[(size_t)k * DH + j], acc);
  size_t o = ((size_t)(j >> 2) * NROWS + r) * 4 + (j & 3);
  h1[o] = acc; h2[o] = acc; h3[o] = acc;
  if (blockIdx.y == 0 && lane == 0) {
    tok[r] = SOS_T;
    eos[r] = 0;
    outi[(size_t)r * MAXLEN] = SOS_T;               // X_gen[:,0] = SOS
    outi[(size_t)NROWS * MAXLEN + r] = MAXLEN;      // seq_lens init
  }
}

// ---------------- fused GRU cell, transposed mapping ----------------
// lane -> row (64 rows/wave, 256/wg), blockIdx.y -> j-tile of 8.
// Weights: repacked [jt][k][3][8], wave-uniform -> s_load (K$, shared by waves).
// Activations/state: P4 packed -> per-lane coalesced dwordx4 loads/stores.
template <bool IS_L0>
__global__ __launch_bounds__(256, 4) void gru_kernel(
    const float* __restrict__ XinP,   // P4 [DH/4][NROWS][4]   (L1/L2)
    const int*   __restrict__ tok,    // [NROWS]               (L0)
    const float* __restrict__ G0,     // [VOC][3*DH], has b_ih (L0)
    const float* __restrict__ HprevP, // P4
    const float* __restrict__ WiP,    // repacked [64][DH][3][8] (L1/L2)
    const float* __restrict__ WhP,    // repacked [64][DH][3][8]
    const float* __restrict__ bi,     // [3*DH]                (L1/L2)
    const float* __restrict__ bh,     // [3*DH]
    float* __restrict__ HnewP) {
  int lane = threadIdx.x & 63;
  int wave = __builtin_amdgcn_readfirstlane((int)(threadIdx.x >> 6));
  int r  = blockIdx.x * 256 + wave * 64 + lane;  // grid.x = NROWS/256
  int j0 = blockIdx.y * 8;                       // grid.y = DH/8
  int jt = blockIdx.y;

  float aA[8], aB[8], aC[8], aD[8];  // r-acc, z-acc, i_n, h_n
  if constexpr (IS_L0) {
    int t = tok[r];
    const float4* gr = (const float4*)(G0 + (size_t)t * (3 * DH) + j0);
    const float4* gz = (const float4*)(G0 + (size_t)t * (3 * DH) + DH + j0);
    const float4* gn = (const float4*)(G0 + (size_t)t * (3 * DH) + 2 * DH + j0);
    float4 r0 = gr[0], r1 = gr[1];
    float4 z0 = gz[0], z1 = gz[1];
    float4 n0 = gn[0], n1 = gn[1];
    float grv[8] = {r0.x, r0.y, r0.z, r0.w, r1.x, r1.y, r1.z, r1.w};
    float gzv[8] = {z0.x, z0.y, z0.z, z0.w, z1.x, z1.y, z1.z, z1.w};
    float gnv[8] = {n0.x, n0.y, n0.z, n0.w, n1.x, n1.y, n1.z, n1.w};
    #pragma unroll
    for (int jj = 0; jj < 8; ++jj) {
      aA[jj] = grv[jj] + bh[j0 + jj];
      aB[jj] = gzv[jj] + bh[DH + j0 + jj];
      aC[jj] = gnv[jj];
      aD[jj] = bh[2 * DH + j0 + jj];
    }
  } else {
    #pragma unroll
    for (int jj = 0; jj < 8; ++jj) {
      aA[jj] = bi[j0 + jj] + bh[j0 + jj];
      aB[jj] = bi[DH + j0 + jj] + bh[DH + j0 + jj];
      aC[jj] = bi[2 * DH + j0 + jj];
      aD[jj] = bh[2 * DH + j0 + jj];
    }
    // phase 1: gi += x @ Wi^T
    const float4* xp = (const float4*)XinP;
    const float* wb = WiP + (size_t)jt * DH * 24;
    #pragma unroll 2
    for (int k4 = 0; k4 < DH / 4; ++k4) {
      float4 x = xp[(size_t)k4 * NROWS + r];   // per-lane coalesced
      float xe[4] = {x.x, x.y, x.z, x.w};
      #pragma unroll
      for (int kk = 0; kk < 4; ++kk) {
        const float* wk = wb + (size_t)(4 * k4 + kk) * 24;  // uniform -> s_load
        #pragma unroll
        for (int jj = 0; jj < 8; ++jj) {
          aA[jj] = fmaf(xe[kk], wk[jj], aA[jj]);
          aB[jj] = fmaf(xe[kk], wk[8 + jj], aB[jj]);
          aC[jj] = fmaf(xe[kk], wk[16 + jj], aC[jj]);
        }
      }
    }
  }
  // phase 2: gh += h @ Wh^T
  {
    const float4* hp = (const float4*)HprevP;
    const float* wb = WhP + (size_t)jt * DH * 24;
    #pragma unroll 2
    for (int k4 = 0; k4 < DH / 4; ++k4) {
      float4 h = hp[(size_t)k4 * NROWS + r];   // per-lane coalesced
      float he[4] = {h.x, h.y, h.z, h.w};
      #pragma unroll
      for (int kk = 0; kk < 4; ++kk) {
        const float* wk = wb + (size_t)(4 * k4 + kk) * 24;  // uniform -> s_load
        #pragma unroll
        for (int jj = 0; jj < 8; ++jj) {
          aA[jj] = fmaf(he[kk], wk[jj], aA[jj]);
          aB[jj] = fmaf(he[kk], wk[8 + jj], aB[jj]);
          aD[jj] = fmaf(he[kk], wk[16 + jj], aD[jj]);
        }
      }
    }
  }
  // epilogue: gates + blend, coalesced packed stores
  const float4* hp = (const float4*)HprevP;
  float4 p0 = hp[(size_t)(j0 >> 2) * NROWS + r];
  float4 p1 = hp[(size_t)((j0 >> 2) + 1) * NROWS + r];
  float hpv[8] = {p0.x, p0.y, p0.z, p0.w, p1.x, p1.y, p1.z, p1.w};
  float out[8];
  #pragma unroll
  for (int jj = 0; jj < 8; ++jj) {
    float rg = 1.f / (1.f + expf(-aA[jj]));
    float zg = 1.f / (1.f + expf(-aB[jj]));
    float n  = tanhf(aC[jj] + rg * aD[jj]);
    out[jj] = (1.f - zg) * n + zg * hpv[jj];
  }
  float4* o4 = (float4*)HnewP;
  o4[(size_t)(j0 >> 2) * NROWS + r]       = make_float4(out[0], out[1], out[2], out[3]);
  o4[(size_t)((j0 >> 2) + 1) * NROWS + r] = make_float4(out[4], out[5], out[6], out[7]);
}

// ---------------- logits + argmax + EOS bookkeeping ----------------
// wave -> 4 rows (weight reuse x4), lane = vocab id; h3 in P4 layout.
__global__ __launch_bounds__(256) void argmax_kernel(
    const float* __restrict__ H3P, const float* __restrict__ h2vP,
    const float* __restrict__ h2v_b,
    int* __restrict__ tok, int* __restrict__ eos,
    int* __restrict__ outi, int t) {
  int lane = threadIdx.x & 63;
  int wave = __builtin_amdgcn_readfirstlane((int)(threadIdx.x >> 6));
  int r0 = blockIdx.x * 16 + wave * 4;    // grid.x = NROWS/16
  float acc[4];
  float b = h2v_b[lane];
  #pragma unroll
  for (int i = 0; i < 4; ++i) acc[i] = b;
  const float4* h4 = (const float4*)H3P;
  const float4* w4 = (const float4*)h2vP;
  #pragma unroll 2
  for (int k4 = 0; k4 < DH / 4; ++k4) {
    float4 w = w4[(size_t)k4 * VOC + lane];       // coalesced vector
    #pragma unroll
    for (int i = 0; i < 4; ++i) {
      float4 h = h4[(size_t)k4 * NROWS + (r0 + i)];  // wave-uniform -> s_load
      acc[i] = fmaf(h.x, w.x, acc[i]); acc[i] = fmaf(h.y, w.y, acc[i]);
      acc[i] = fmaf(h.z, w.z, acc[i]); acc[i] = fmaf(h.w, w.w, acc[i]);
    }
  }
  #pragma unroll
  for (int i = 0; i < 4; ++i) {
    // argmax across 64 lanes; tie -> lowest index (jnp.argmax = first max)
    float v = acc[i]; int idx = lane;
    #pragma unroll
    for (int off = 32; off >= 1; off >>= 1) {
      float v2 = __shfl_xor(v, off);
      int   i2 = __shfl_xor(idx, off);
      if (v2 > v || (v2 == v && i2 < idx)) { v = v2; idx = i2; }
    }
    if (lane == 0) {
      int r = r0 + i;
      int e = eos[r];
      int x_next = idx;
      outi[(size_t)r * MAXLEN + t] = e ? PAD_T : x_next;
      if (!e && x_next == EOS_T) {
        outi[(size_t)NROWS * MAXLEN + r] = t + 1;  // seq_lens
        eos[r] = 1;
      }
      tok[r] = x_next;  // raw x_next feeds back
    }
  }
}

// ---------------- host-side orchestration ----------------
extern "C" void kernel_launch(void* const* d_in, const int* in_sizes, int n_in,
                              void* d_out, int out_size, void* d_ws, size_t ws_size,
                              hipStream_t stream) {
  const float* Z      = (const float*)d_in[0];
  const float* emb    = (const float*)d_in[1];
  const float* z2h_w  = (const float*)d_in[2];
  const float* z2h_b  = (const float*)d_in[3];
  const float* W_ih0  = (const float*)d_in[4];
  const float* W_hh0  = (const float*)d_in[5];
  const float* b_ih0  = (const float*)d_in[6];
  const float* b_hh0  = (const float*)d_in[7];
  const float* W_ih1  = (const float*)d_in[8];
  const float* W_hh1  = (const float*)d_in[9];
  const float* b_ih1  = (const float*)d_in[10];
  const float* b_hh1  = (const float*)d_in[11];
  const float* W_ih2  = (const float*)d_in[12];
  const float* W_hh2  = (const float*)d_in[13];
  const float* b_ih2  = (const float*)d_in[14];
  const float* b_hh2  = (const float*)d_in[15];
  const float* h2v_w  = (const float*)d_in[16];
  const float* h2v_b  = (const float*)d_in[17];
  int* outi = (int*)d_out;

  // workspace layout (all chunks 16B-aligned)
  float* p = (float*)d_ws;
  float* WhP0 = p; p += (size_t)64 * DH * 24;     // repacked [64][512][3][8]
  float* WiP1 = p; p += (size_t)64 * DH * 24;
  float* WhP1 = p; p += (size_t)64 * DH * 24;
  float* WiP2 = p; p += (size_t)64 * DH * 24;
  float* WhP2 = p; p += (size_t)64 * DH * 24;
  float* WiT0 = p; p += (size_t)DE * 3 * DH;      // plain transpose, for G0
  float* G0   = p; p += (size_t)VOC * 3 * DH;
  float* z2hT = p; p += (size_t)DZ * DH;
  float* h2vP = p; p += (size_t)DH * VOC;         // packed [k/4][VOC][4]
  float* h1a = p; p += (size_t)NROWS * DH;
  float* h1b = p; p += (size_t)NROWS * DH;
  float* h2a = p; p += (size_t)NROWS * DH;
  float* h2b = p; p += (size_t)NROWS * DH;
  float* h3a = p; p += (size_t)NROWS * DH;
  float* h3b = p; p += (size_t)NROWS * DH;
  int* tokb = (int*)p;
  int* eosb = tokb + NROWS;

  // one-time weight prep
  {
    int nblk = (64 * DH * 24) / 256;
    repack_w<<<nblk, 256, 0, stream>>>(W_hh0, WhP0, DH);
    repack_w<<<nblk, 256, 0, stream>>>(W_ih1, WiP1, DH);
    repack_w<<<nblk, 256, 0, stream>>>(W_hh1, WhP1, DH);
    repack_w<<<nblk, 256, 0, stream>>>(W_ih2, WiP2, DH);
    repack_w<<<nblk, 256, 0, stream>>>(W_hh2, WhP2, DH);
  }
  transpose_k<<<dim3(DE / 32, (3 * DH) / 32), dim3(32, 8), 0, stream>>>(
      W_ih0, WiT0, 3 * DH, DE);
  transpose_k<<<dim3(DZ / 32, DH / 32), dim3(32, 8), 0, stream>>>(
      z2h_w, z2hT, DH, DZ);
  repack_k<<<dim3(VOC, DH / 128), 128, 0, stream>>>(h2v_w, h2vP, VOC, DH);
  build_g0<<<dim3(VOC, (3 * DH) / 256), 256, 0, stream>>>(emb, WiT0, b_ih0, G0);

  init_kernel<<<dim3(NROWS / 4, DH / 64), 256, 0, stream>>>(
      Z, z2hT, z2h_b, h1a, h2a, h3a, tokb, eosb, outi);

  float* h1p = h1a; float* h1n = h1b;
  float* h2p = h2a; float* h2n = h2b;
  float* h3p = h3a; float* h3n = h3b;
  for (int t = 1; t < MAXLEN; ++t) {
    gru_kernel<true><<<dim3(NROWS / 256, DH / 8), 256, 0, stream>>>(
        nullptr, tokb, G0, h1p, nullptr, WhP0, nullptr, b_hh0, h1n);
    gru_kernel<false><<<dim3(NROWS / 256, DH / 8), 256, 0, stream>>>(
        h1n, nullptr, nullptr, h2p, WiP1, WhP1, b_ih1, b_hh1, h2n);
    gru_kernel<false><<<dim3(NROWS / 256, DH / 8), 256, 0, stream>>>(
        h2n, nullptr, nullptr, h3p, WiP2, WhP2, b_ih2, b_hh2, h3n);
    argmax_kernel<<<dim3(NROWS / 16), 256, 0, stream>>>(
        h3n, h2vP, h2v_b, tokb, eosb, outi, t);
    float* tmp;
    tmp = h1p; h1p = h1n; h1n = tmp;
    tmp = h2p; h2p = h2n; h2n = tmp;
    tmp = h3p; h3p = h3n; h3n = tmp;
  }
}